// Round 9
// baseline (76.811 us; speedup 1.0000x reference)
//
#include <hip/hip_runtime.h>
#include <hip/hip_fp16.h>

// SoftNCutsLoss on MI355X — R22.
// batch: (4,1,32,32,32) f32, preds: (4,8,32,32,32) f32 -> out: (4,) f32
//
// R22 = R21 (76.19us best) + latency-tail fixes; arithmetic byte-identical.
// R21 post-mortem: fma_mix VALU cut delivered per-model (-1.5us) => main
// (~20us) is VALU-issue + latency bound; per-entry VALU now ~15 (within ~15%
// of the algorithm's floor), f16-packed LDS layout is DS-optimal (pk_fma_f32
// variant rejected on paper: f32 preds double DS bytes, 18->38 cyc/entry).
// Changes:
//  (a) own-voxel loads (b_own + q[0..7], 9 global_load_dword) hoisted BEFORE
//      the accumulate loop — they sit in flight under ~4000 cyc of compute
//      instead of serializing an L2 latency at loop exit. The R16-era "load
//      after loop" was for a 64-VGPR cap; current VGPR_Count=56 under a 128
//      cap — headroom is free.
//  (b) unroll_count(2) -> unroll_count(4): 16 DS reads in flight (was 8),
//      better latency hiding at 4 waves/SIMD; ~4KB loop code, still rolled.
// Everything else R21-proven: rolled __constant__ CTAB, fma_mix inner loop,
// XOR-swizzled epilogue, S-table, two-kernel launch.

#define EPS_F 2.220446049250313e-16f

constexpr int TD = 4, TH = 8, TW = 8;      // tile dims (d,h,w)
constexpr int HDh = 7, HHh = 14, HWh = 14; // halo: x forward-only +3, y/z +-3
constexpr int SYB = 17;                    // halo h-stride
constexpr int SXB = HHh * SYB;             // 238, halo d-stride
constexpr int NB  = 6 * SXB + 13 * SYB + 13 + 1;  // 1663 voxel slots
constexpr int NT = 512;                    // threads per block (8 waves)
constexpr int NBLK = 512;                  // 4 batches * 128 tiles
constexpr int NTASK = HDh * HHh * 4;       // 392 staging tasks (row x 4 chunks)

// exponent folding: aff = exp2(d2*K1 + c2*K2)
#define K1F (-0.014426950408889634f)       // -0.01 * log2(e)
#define K2F (-0.09016844005556021f)        // -log2(e)/16

struct Ent { int off; float lw; };
struct Tab { Ent e[64]; int n; };

constexpr Tab make_tab(int half) {
    Tab t{};
    t.n = 0;
    for (int dxq = 0; dxq < 4; ++dxq)
        for (int dyi = 0; dyi < 7; ++dyi)
            for (int dzi = 0; dzi < 7; ++dzi) {
                int dy = dyi - 3, dz = dzi - 3;
                if (dxq == 0) {                  // lexicographic positivity
                    if (dy < 0) continue;
                    if (dy == 0 && dz <= 0) continue;
                }
                int c2 = dxq * dxq + dy * dy + dz * dz;
                if (c2 >= 16) continue;          // ball cutoff
                if (((dyi + dzi) & 1) != half) continue;
                t.e[t.n].off = dxq * SXB + dy * SYB + dz;
                t.e[t.n].lw  = (float)c2 * K2F;
                ++t.n;                           // 62 / 63
            }
    // pad to 64: off=0 (reads own voxel, valid), lw=-1e4 -> exp2 -> 0 exactly
    for (int i = t.n; i < 64; ++i) { t.e[i].off = 0; t.e[i].lw = -10000.0f; }
    t.n = 64;
    return t;
}

struct CTab2 { Ent e[2][64]; };
constexpr CTab2 make_ctab() {
    CTab2 c{};
    const Tab a = make_tab(0), b = make_tab(1);
    for (int i = 0; i < 64; ++i) { c.e[0][i] = a.e[i]; c.e[1][i] = b.e[i]; }
    return c;
}
__constant__ CTab2 CTAB = make_ctab();

// ---------- constexpr border-S table: S(class_d, class_h, class_w) ----------
constexpr float W16[16] = {
    1.0f,                    0.93941306281347578611f, 0.88249690258459546286f,
    0.82902911818040034301f, 0.77880078307140486825f, 0.73161562894664190813f,
    0.68728927879097219970f, 0.64565423513106973593f, 0.60653065971263342360f,
    0.56978282473092302544f, 0.53526142851899028012f, 0.50283157797094090696f,
    0.47236655274101470713f, 0.44374731008100323837f, 0.41686201967850837523f,
    0.39160740400665634335f };

struct STab { float s[343]; };
constexpr STab make_stab() {
    STab t{};
    for (int a = 0; a < 7; ++a)
        for (int b = 0; b < 7; ++b)
            for (int c = 0; c < 7; ++c) {
                const int pa = a < 3 ? a : (a == 3 ? 16 : a + 25);
                const int pb = b < 3 ? b : (b == 3 ? 16 : b + 25);
                const int pc = c < 3 ? c : (c == 3 ? 16 : c + 25);
                float s = 0.f;
                for (int dx = -3; dx <= 3; ++dx)
                    for (int dy = -3; dy <= 3; ++dy)
                        for (int dz = -3; dz <= 3; ++dz) {
                            const int c2 = dx * dx + dy * dy + dz * dz;
                            if (c2 >= 16) continue;
                            const bool neg = (dx < 0) ||
                                (dx == 0 && (dy < 0 || (dy == 0 && dz < 0)));
                            if (!neg) continue;
                            const bool in = (pa + dx) >= 0 && (pa + dx) < 32 &&
                                            (pb + dy) >= 0 && (pb + dy) < 32 &&
                                            (pc + dz) >= 0 && (pc + dz) < 32;
                            if (!in) s += W16[c2];
                        }
                t.s[(a * 7 + b) * 7 + c] = s;
            }
    return t;
}
__constant__ STab STAB = make_stab();

__device__ __forceinline__ int bcls(int p) {
    return p < 3 ? p : (p > 28 ? p - 25 : 3);
}

__device__ __forceinline__ unsigned pack2(float a, float b) {
    return (unsigned)__half_as_ushort(__float2half(a)) |
           ((unsigned)__half_as_ushort(__float2half(b)) << 16);
}

// f32 += f32 * f16(lo/hi of packed dword) via v_fma_mix_f32 (exact, 1 inst).
__device__ __forceinline__ void fma_mix_lo(float& acc, float aff, unsigned pk) {
    asm("v_fma_mix_f32 %0, %1, %2, %0 op_sel_hi:[0,1,0]"
        : "+v"(acc) : "v"(aff), "v"(pk));
}
__device__ __forceinline__ void fma_mix_hi(float& acc, float aff, unsigned pk) {
    asm("v_fma_mix_f32 %0, %1, %2, %0 op_sel:[0,1,0] op_sel_hi:[0,1,0]"
        : "+v"(acc) : "v"(aff), "v"(pk));
}

// Rolled accumulate loop (~4KB code, shared by both halves). Table entries
// are wave-uniform scalar loads; DS addresses are vown + sgpr offset.
__device__ __forceinline__ void accum_rolled(const float* __restrict__ sB,
                                             const uint4* __restrict__ sPk,
                                             int vown, float b_own,
                                             const Ent* __restrict__ tab,
                                             float acc[9]) {
#pragma clang loop unroll_count(4)
    for (int i = 0; i < 64; i += 4) {
        float sb[4];
        uint4 pk[4];
        float lwv[4];
#pragma unroll
        for (int j = 0; j < 4; ++j) {
            const int off = tab[i + j].off;     // s_load_dwordx2 (uniform)
            lwv[j] = tab[i + j].lw;
            const int nv = vown + off;
            sb[j] = sB[nv];
            pk[j] = sPk[nv];
        }
#pragma unroll
        for (int j = 0; j < 4; ++j) {
            const float d = b_own - sb[j];
            const float aff =
                __builtin_amdgcn_exp2f(__builtin_fmaf(d * d, K1F, lwv[j]));
            acc[8] += aff;
            fma_mix_lo(acc[0], aff, pk[j].x);
            fma_mix_hi(acc[1], aff, pk[j].x);
            fma_mix_lo(acc[2], aff, pk[j].y);
            fma_mix_hi(acc[3], aff, pk[j].y);
            fma_mix_lo(acc[4], aff, pk[j].z);
            fma_mix_hi(acc[5], aff, pk[j].z);
            fma_mix_lo(acc[6], aff, pk[j].w);
            fma_mix_hi(acc[7], aff, pk[j].w);
        }
    }
}

__global__ __launch_bounds__(NT, 4)
void softncuts_main(const float* __restrict__ batch,
                    const float* __restrict__ preds,
                    float* __restrict__ partials) {
    __shared__ float sB[NB];            // batch halo, f32 (6.5 KB)
    __shared__ uint4 sPk[NB];           // preds halo, 8 x f16 packed (26 KB)
    __shared__ float valsT[NT * 20];    // epilogue transpose, row stride 20 (40 KB)

    const int bid  = blockIdx.x;
    const int bb   = bid >> 7;          // batch index 0..3
    const int tile = bid & 127;
    const int tw = tile & 3;            // -> w0 = tw*8
    const int th = (tile >> 2) & 3;     // -> h0 = th*8
    const int td = tile >> 4;           // -> d0 = td*4
    const int d0 = td * TD, h0 = th * TH, w0 = tw * TW;

    const int tid  = threadIdx.x;
    const int half = tid >> 8;          // 0/1, wave-uniform (waves 0-3 vs 4-7)
    const int vtid = tid & 255;
    const int lw = vtid & 7;            // 0..7
    const int lh = (vtid >> 3) & 7;     // 0..7
    const int ld = vtid >> 6;           // 0..3

    const float* bbase = batch + (size_t)bb * 32768;
    const float* pbase = preds + (size_t)bb * 8 * 32768;

    // ---- own voxel loads issued FIRST (in flight across staging + loop) ----
    const int gdo = d0 + ld, gho = h0 + lh, gwo = w0 + lw;
    const int sidx_own = (gdo * 32 + gho) * 32 + gwo;
    const float b_own = bbase[sidx_own];
    float q[8];
#pragma unroll
    for (int k = 0; k < 8; ++k) q[k] = pbase[sidx_own + k * 32768];

    // ---- stage forward-x halo, float4-vectorized along w ----
    if (tid < NTASK) {
        const int t   = tid;
        const int c   = t & 3;
        const int row = t >> 2;
        const int hh  = row % HHh;
        const int hd  = row / HHh;
        const int gd  = d0 + hd;
        const int gh  = h0 + hh - 3;
        const int gw0 = w0 - 4 + c * 4;
        const int hwb = c * 4 - 1;
        const bool fast = (gd < 32) & ((unsigned)gh < 32u) & (gw0 >= 0) & (gw0 + 3 < 32);
        if (fast) {
            const int sidx = (gd * 32 + gh) * 32 + gw0;   // 16B-aligned
            float4 pv[9];
            pv[0] = *(const float4*)(bbase + sidx);
#pragma unroll
            for (int k = 0; k < 8; ++k)
                pv[k + 1] = *(const float4*)(pbase + sidx + k * 32768);
#pragma unroll
            for (int e = 0; e < 4; ++e) {
                const int hw = hwb + e;
                if (hw < 0 || hw >= HWh) continue;
                const int f = hd * SXB + hh * SYB + hw;
                sB[f] = ((const float*)&pv[0])[e];
                unsigned u[4];
#pragma unroll
                for (int k = 0; k < 4; ++k)
                    u[k] = pack2(((const float*)&pv[2 * k + 1])[e],
                                 ((const float*)&pv[2 * k + 2])[e]);
                sPk[f] = make_uint4(u[0], u[1], u[2], u[3]);
            }
        } else {
#pragma unroll
            for (int e = 0; e < 4; ++e) {
                const int hw = hwb + e;
                if (hw < 0 || hw >= HWh) continue;
                const int gw = gw0 + e;
                const bool in = (gd < 32) & ((unsigned)gh < 32u) & ((unsigned)gw < 32u);
                const int sidx = (gd * 32 + gh) * 32 + gw;
                const int f = hd * SXB + hh * SYB + hw;
                sB[f] = in ? bbase[sidx] : EPS_F;
                unsigned u[4];
#pragma unroll
                for (int k = 0; k < 4; ++k)
                    u[k] = pack2(in ? pbase[sidx + (2 * k) * 32768]     : 0.f,
                                 in ? pbase[sidx + (2 * k + 1) * 32768] : 0.f);
                sPk[f] = make_uint4(u[0], u[1], u[2], u[3]);
            }
        }
    }
    __syncthreads();

    const int vown = ld * SXB + (lh + 3) * SYB + (lw + 3);

    float acc[9];
#pragma unroll
    for (int i = 0; i < 9; ++i) acc[i] = 0.f;

    // uniform table base -> scalar loads inside the rolled loop
    const int halfu = __builtin_amdgcn_readfirstlane(half);
    accum_rolled(sB, sPk, vown, b_own, CTAB.e[halfu], acc);

    // ---- self + pad terms (table lookup, half==0 threads only) ----
    float selfpad = 0.f;
    if (half == 0) {
        const float S = STAB.s[(bcls(gdo) * 7 + bcls(gho)) * 7 + bcls(gwo)];
        const float db = b_own - EPS_F;
        selfpad = 1.f + S * __expf(db * db * -0.01f);
    }

    // ---- per-lane contributions (voxel shared by 2 threads; self terms once) ----
    float vals[16];
#pragma unroll
    for (int k = 0; k < 8; ++k) {
        vals[k]     = q[k] * (2.f * acc[k] + ((half == 0) ? q[k] : 0.f));
        vals[8 + k] = q[k] * (acc[8] + selfpad) + acc[k];
    }

    // ---- LDS-transpose block reduction, XOR-swizzled quads ----
    // write: float4 #j at quad j^sw (sw=(tid>>3)&3): 8-way -> 2-way (free)
    // read:  value val of row rr at quad (val>>2)^((rr>>3)&3): 4-way -> 0
    {
        float* vr = &valsT[tid * 20];                 // 80 B rows, 16B aligned
        const int sw = (tid >> 3) & 3;
        ((float4*)vr)[0 ^ sw] = make_float4(vals[0],  vals[1],  vals[2],  vals[3]);
        ((float4*)vr)[1 ^ sw] = make_float4(vals[4],  vals[5],  vals[6],  vals[7]);
        ((float4*)vr)[2 ^ sw] = make_float4(vals[8],  vals[9],  vals[10], vals[11]);
        ((float4*)vr)[3 ^ sw] = make_float4(vals[12], vals[13], vals[14], vals[15]);
    }
    __syncthreads();
    {
        const int val = tid >> 5;                     // 0..15
        const int r   = tid & 31;                     // 32 readers per value
        const int A = val >> 2, B = val & 3;
        float s = 0.f;
#pragma unroll
        for (int k = 0; k < 16; ++k) {
            const int rr = r + 32 * k;
            const int col = ((A ^ ((rr >> 3) & 3)) << 2) + B;
            s += valsT[rr * 20 + col];
        }
        for (int off = 16; off; off >>= 1) s += __shfl_down(s, off, 32);
        if (r == 0) partials[val * NBLK + bid] = s;
    }
}

__global__ __launch_bounds__(1024)
void softncuts_finalize(const float* __restrict__ partials,
                        float* __restrict__ out) {
    __shared__ float red[64];
    const int tid = threadIdx.x;          // 0..1023
    const int group = tid >> 4;           // 0..63 = bb*16 + slot
    const int j0 = tid & 15;
    const int slot = group & 15;
    const int bb = group >> 4;

    const float* p = partials + slot * NBLK + bb * 128;   // 128 tiles per batch
    float s = 0.f;
#pragma unroll
    for (int k = 0; k < 8; ++k) s += p[j0 + 16 * k];
    for (int off = 8; off; off >>= 1) s += __shfl_down(s, off, 16);
    if (j0 == 0) red[group] = s;
    __syncthreads();

    if (tid < 4) {
        float accv = 0.f;
#pragma unroll
        for (int k = 0; k < 8; ++k)
            accv += red[tid * 16 + k] / red[tid * 16 + 8 + k];
        out[tid] = 8.0f - accv;
    }
}

extern "C" void kernel_launch(void* const* d_in, const int* in_sizes, int n_in,
                              void* d_out, int out_size, void* d_ws, size_t ws_size,
                              hipStream_t stream) {
    const float* batch = (const float*)d_in[0];
    const float* preds = (const float*)d_in[1];
    float* out      = (float*)d_out;
    float* partials = (float*)d_ws;   // 16*NBLK floats = 32 KB

    softncuts_main<<<dim3(NBLK), dim3(NT), 0, stream>>>(batch, preds, partials);
    softncuts_finalize<<<dim3(1), dim3(1024), 0, stream>>>(partials, out);
}

// Round 10
// 76.058 us; speedup vs baseline: 1.0099x; 1.0099x over previous
//
#include <hip/hip_runtime.h>
#include <hip/hip_fp16.h>

// SoftNCutsLoss on MI355X — R23 (= R21 exact revert; best measured 76.19us).
// batch: (4,1,32,32,32) f32, preds: (4,8,32,32,32) f32 -> out: (4,) f32
//
// R22 post-mortem: hoisting the 9 own-voxel loads BEFORE staging made them
// the oldest outstanding VMEM ops; staging's s_waitcnt vmcnt(N) (in-order
// counter) had to drain them -> serialized the staging front (+0.6us).
// R21's placement (after staging barrier, before loop) lets them drain under
// the accumulate loop. unroll_count stays 2 (R22's 4 was confounded, expected
// value ~0 per R17's code-size measurement).
//
// Final structure (ledger of what's proven):
//  - rolled __constant__ CTAB accumulate loop (R17: -0.8us vs unrolled 24KB)
//  - v_fma_mix_f32 inner loop, bit-identical f16 math (R21: -1.5us, VALU cut)
//  - XOR-swizzled valsT epilogue (R20-verified bank math; R15: epilogue
//    rebuild -2.4us with S-table)
//  - constexpr 343-entry border S-table (R15)
//  - two-kernel launch (R20 fusion measured neutral)
// Neutral axes (tested, abandoned): 2x occupancy (R16), DS -41% (R18),
// fence-free fused finalize (R20), load hoist + ILP x2 (R22).

#define EPS_F 2.220446049250313e-16f

constexpr int TD = 4, TH = 8, TW = 8;      // tile dims (d,h,w)
constexpr int HDh = 7, HHh = 14, HWh = 14; // halo: x forward-only +3, y/z +-3
constexpr int SYB = 17;                    // halo h-stride
constexpr int SXB = HHh * SYB;             // 238, halo d-stride
constexpr int NB  = 6 * SXB + 13 * SYB + 13 + 1;  // 1663 voxel slots
constexpr int NT = 512;                    // threads per block (8 waves)
constexpr int NBLK = 512;                  // 4 batches * 128 tiles
constexpr int NTASK = HDh * HHh * 4;       // 392 staging tasks (row x 4 chunks)

// exponent folding: aff = exp2(d2*K1 + c2*K2)
#define K1F (-0.014426950408889634f)       // -0.01 * log2(e)
#define K2F (-0.09016844005556021f)        // -log2(e)/16

struct Ent { int off; float lw; };
struct Tab { Ent e[64]; int n; };

constexpr Tab make_tab(int half) {
    Tab t{};
    t.n = 0;
    for (int dxq = 0; dxq < 4; ++dxq)
        for (int dyi = 0; dyi < 7; ++dyi)
            for (int dzi = 0; dzi < 7; ++dzi) {
                int dy = dyi - 3, dz = dzi - 3;
                if (dxq == 0) {                  // lexicographic positivity
                    if (dy < 0) continue;
                    if (dy == 0 && dz <= 0) continue;
                }
                int c2 = dxq * dxq + dy * dy + dz * dz;
                if (c2 >= 16) continue;          // ball cutoff
                if (((dyi + dzi) & 1) != half) continue;
                t.e[t.n].off = dxq * SXB + dy * SYB + dz;
                t.e[t.n].lw  = (float)c2 * K2F;
                ++t.n;                           // 62 / 63
            }
    // pad to 64: off=0 (reads own voxel, valid), lw=-1e4 -> exp2 -> 0 exactly
    for (int i = t.n; i < 64; ++i) { t.e[i].off = 0; t.e[i].lw = -10000.0f; }
    t.n = 64;
    return t;
}

struct CTab2 { Ent e[2][64]; };
constexpr CTab2 make_ctab() {
    CTab2 c{};
    const Tab a = make_tab(0), b = make_tab(1);
    for (int i = 0; i < 64; ++i) { c.e[0][i] = a.e[i]; c.e[1][i] = b.e[i]; }
    return c;
}
__constant__ CTab2 CTAB = make_ctab();

// ---------- constexpr border-S table: S(class_d, class_h, class_w) ----------
constexpr float W16[16] = {
    1.0f,                    0.93941306281347578611f, 0.88249690258459546286f,
    0.82902911818040034301f, 0.77880078307140486825f, 0.73161562894664190813f,
    0.68728927879097219970f, 0.64565423513106973593f, 0.60653065971263342360f,
    0.56978282473092302544f, 0.53526142851899028012f, 0.50283157797094090696f,
    0.47236655274101470713f, 0.44374731008100323837f, 0.41686201967850837523f,
    0.39160740400665634335f };

struct STab { float s[343]; };
constexpr STab make_stab() {
    STab t{};
    for (int a = 0; a < 7; ++a)
        for (int b = 0; b < 7; ++b)
            for (int c = 0; c < 7; ++c) {
                const int pa = a < 3 ? a : (a == 3 ? 16 : a + 25);
                const int pb = b < 3 ? b : (b == 3 ? 16 : b + 25);
                const int pc = c < 3 ? c : (c == 3 ? 16 : c + 25);
                float s = 0.f;
                for (int dx = -3; dx <= 3; ++dx)
                    for (int dy = -3; dy <= 3; ++dy)
                        for (int dz = -3; dz <= 3; ++dz) {
                            const int c2 = dx * dx + dy * dy + dz * dz;
                            if (c2 >= 16) continue;
                            const bool neg = (dx < 0) ||
                                (dx == 0 && (dy < 0 || (dy == 0 && dz < 0)));
                            if (!neg) continue;
                            const bool in = (pa + dx) >= 0 && (pa + dx) < 32 &&
                                            (pb + dy) >= 0 && (pb + dy) < 32 &&
                                            (pc + dz) >= 0 && (pc + dz) < 32;
                            if (!in) s += W16[c2];
                        }
                t.s[(a * 7 + b) * 7 + c] = s;
            }
    return t;
}
__constant__ STab STAB = make_stab();

__device__ __forceinline__ int bcls(int p) {
    return p < 3 ? p : (p > 28 ? p - 25 : 3);
}

__device__ __forceinline__ unsigned pack2(float a, float b) {
    return (unsigned)__half_as_ushort(__float2half(a)) |
           ((unsigned)__half_as_ushort(__float2half(b)) << 16);
}

// f32 += f32 * f16(lo/hi of packed dword) via v_fma_mix_f32 (exact, 1 inst).
__device__ __forceinline__ void fma_mix_lo(float& acc, float aff, unsigned pk) {
    asm("v_fma_mix_f32 %0, %1, %2, %0 op_sel_hi:[0,1,0]"
        : "+v"(acc) : "v"(aff), "v"(pk));
}
__device__ __forceinline__ void fma_mix_hi(float& acc, float aff, unsigned pk) {
    asm("v_fma_mix_f32 %0, %1, %2, %0 op_sel:[0,1,0] op_sel_hi:[0,1,0]"
        : "+v"(acc) : "v"(aff), "v"(pk));
}

// Rolled accumulate loop (~2KB code, shared by both halves). Table entries
// are wave-uniform scalar loads; DS addresses are vown + sgpr offset.
__device__ __forceinline__ void accum_rolled(const float* __restrict__ sB,
                                             const uint4* __restrict__ sPk,
                                             int vown, float b_own,
                                             const Ent* __restrict__ tab,
                                             float acc[9]) {
#pragma clang loop unroll_count(2)
    for (int i = 0; i < 64; i += 4) {
        float sb[4];
        uint4 pk[4];
        float lwv[4];
#pragma unroll
        for (int j = 0; j < 4; ++j) {
            const int off = tab[i + j].off;     // s_load_dwordx2 (uniform)
            lwv[j] = tab[i + j].lw;
            const int nv = vown + off;
            sb[j] = sB[nv];
            pk[j] = sPk[nv];
        }
#pragma unroll
        for (int j = 0; j < 4; ++j) {
            const float d = b_own - sb[j];
            const float aff =
                __builtin_amdgcn_exp2f(__builtin_fmaf(d * d, K1F, lwv[j]));
            acc[8] += aff;
            fma_mix_lo(acc[0], aff, pk[j].x);
            fma_mix_hi(acc[1], aff, pk[j].x);
            fma_mix_lo(acc[2], aff, pk[j].y);
            fma_mix_hi(acc[3], aff, pk[j].y);
            fma_mix_lo(acc[4], aff, pk[j].z);
            fma_mix_hi(acc[5], aff, pk[j].z);
            fma_mix_lo(acc[6], aff, pk[j].w);
            fma_mix_hi(acc[7], aff, pk[j].w);
        }
    }
}

__global__ __launch_bounds__(NT, 4)
void softncuts_main(const float* __restrict__ batch,
                    const float* __restrict__ preds,
                    float* __restrict__ partials) {
    __shared__ float sB[NB];            // batch halo, f32 (6.5 KB)
    __shared__ uint4 sPk[NB];           // preds halo, 8 x f16 packed (26 KB)
    __shared__ float valsT[NT * 20];    // epilogue transpose, row stride 20 (40 KB)

    const int bid  = blockIdx.x;
    const int bb   = bid >> 7;          // batch index 0..3
    const int tile = bid & 127;
    const int tw = tile & 3;            // -> w0 = tw*8
    const int th = (tile >> 2) & 3;     // -> h0 = th*8
    const int td = tile >> 4;           // -> d0 = td*4
    const int d0 = td * TD, h0 = th * TH, w0 = tw * TW;

    const int tid  = threadIdx.x;
    const int half = tid >> 8;          // 0/1, wave-uniform (waves 0-3 vs 4-7)
    const int vtid = tid & 255;
    const int lw = vtid & 7;            // 0..7
    const int lh = (vtid >> 3) & 7;     // 0..7
    const int ld = vtid >> 6;           // 0..3

    const float* bbase = batch + (size_t)bb * 32768;
    const float* pbase = preds + (size_t)bb * 8 * 32768;

    // ---- stage forward-x halo, float4-vectorized along w ----
    if (tid < NTASK) {
        const int t   = tid;
        const int c   = t & 3;
        const int row = t >> 2;
        const int hh  = row % HHh;
        const int hd  = row / HHh;
        const int gd  = d0 + hd;
        const int gh  = h0 + hh - 3;
        const int gw0 = w0 - 4 + c * 4;
        const int hwb = c * 4 - 1;
        const bool fast = (gd < 32) & ((unsigned)gh < 32u) & (gw0 >= 0) & (gw0 + 3 < 32);
        if (fast) {
            const int sidx = (gd * 32 + gh) * 32 + gw0;   // 16B-aligned
            float4 pv[9];
            pv[0] = *(const float4*)(bbase + sidx);
#pragma unroll
            for (int k = 0; k < 8; ++k)
                pv[k + 1] = *(const float4*)(pbase + sidx + k * 32768);
#pragma unroll
            for (int e = 0; e < 4; ++e) {
                const int hw = hwb + e;
                if (hw < 0 || hw >= HWh) continue;
                const int f = hd * SXB + hh * SYB + hw;
                sB[f] = ((const float*)&pv[0])[e];
                unsigned u[4];
#pragma unroll
                for (int k = 0; k < 4; ++k)
                    u[k] = pack2(((const float*)&pv[2 * k + 1])[e],
                                 ((const float*)&pv[2 * k + 2])[e]);
                sPk[f] = make_uint4(u[0], u[1], u[2], u[3]);
            }
        } else {
#pragma unroll
            for (int e = 0; e < 4; ++e) {
                const int hw = hwb + e;
                if (hw < 0 || hw >= HWh) continue;
                const int gw = gw0 + e;
                const bool in = (gd < 32) & ((unsigned)gh < 32u) & ((unsigned)gw < 32u);
                const int sidx = (gd * 32 + gh) * 32 + gw;
                const int f = hd * SXB + hh * SYB + hw;
                sB[f] = in ? bbase[sidx] : EPS_F;
                unsigned u[4];
#pragma unroll
                for (int k = 0; k < 4; ++k)
                    u[k] = pack2(in ? pbase[sidx + (2 * k) * 32768]     : 0.f,
                                 in ? pbase[sidx + (2 * k + 1) * 32768] : 0.f);
                sPk[f] = make_uint4(u[0], u[1], u[2], u[3]);
            }
        }
    }
    __syncthreads();

    // ---- own voxel values from GLOBAL f32 (full precision for b_own and q) ----
    const int gdo = d0 + ld, gho = h0 + lh, gwo = w0 + lw;
    const int sidx_own = (gdo * 32 + gho) * 32 + gwo;
    const float b_own = bbase[sidx_own];
    float q[8];
#pragma unroll
    for (int k = 0; k < 8; ++k) q[k] = pbase[sidx_own + k * 32768];

    const int vown = ld * SXB + (lh + 3) * SYB + (lw + 3);

    float acc[9];
#pragma unroll
    for (int i = 0; i < 9; ++i) acc[i] = 0.f;

    // uniform table base -> scalar loads inside the rolled loop
    const int halfu = __builtin_amdgcn_readfirstlane(half);
    accum_rolled(sB, sPk, vown, b_own, CTAB.e[halfu], acc);

    // ---- self + pad terms (table lookup, half==0 threads only) ----
    float selfpad = 0.f;
    if (half == 0) {
        const float S = STAB.s[(bcls(gdo) * 7 + bcls(gho)) * 7 + bcls(gwo)];
        const float db = b_own - EPS_F;
        selfpad = 1.f + S * __expf(db * db * -0.01f);
    }

    // ---- per-lane contributions (voxel shared by 2 threads; self terms once) ----
    float vals[16];
#pragma unroll
    for (int k = 0; k < 8; ++k) {
        vals[k]     = q[k] * (2.f * acc[k] + ((half == 0) ? q[k] : 0.f));
        vals[8 + k] = q[k] * (acc[8] + selfpad) + acc[k];
    }

    // ---- LDS-transpose block reduction, XOR-swizzled quads ----
    // write: float4 #j at quad j^sw (sw=(tid>>3)&3): 8-way -> 2-way (free)
    // read:  value val of row rr at quad (val>>2)^((rr>>3)&3): 4-way -> 0
    {
        float* vr = &valsT[tid * 20];                 // 80 B rows, 16B aligned
        const int sw = (tid >> 3) & 3;
        ((float4*)vr)[0 ^ sw] = make_float4(vals[0],  vals[1],  vals[2],  vals[3]);
        ((float4*)vr)[1 ^ sw] = make_float4(vals[4],  vals[5],  vals[6],  vals[7]);
        ((float4*)vr)[2 ^ sw] = make_float4(vals[8],  vals[9],  vals[10], vals[11]);
        ((float4*)vr)[3 ^ sw] = make_float4(vals[12], vals[13], vals[14], vals[15]);
    }
    __syncthreads();
    {
        const int val = tid >> 5;                     // 0..15
        const int r   = tid & 31;                     // 32 readers per value
        const int A = val >> 2, B = val & 3;
        float s = 0.f;
#pragma unroll
        for (int k = 0; k < 16; ++k) {
            const int rr = r + 32 * k;
            const int col = ((A ^ ((rr >> 3) & 3)) << 2) + B;
            s += valsT[rr * 20 + col];
        }
        for (int off = 16; off; off >>= 1) s += __shfl_down(s, off, 32);
        if (r == 0) partials[val * NBLK + bid] = s;
    }
}

__global__ __launch_bounds__(1024)
void softncuts_finalize(const float* __restrict__ partials,
                        float* __restrict__ out) {
    __shared__ float red[64];
    const int tid = threadIdx.x;          // 0..1023
    const int group = tid >> 4;           // 0..63 = bb*16 + slot
    const int j0 = tid & 15;
    const int slot = group & 15;
    const int bb = group >> 4;

    const float* p = partials + slot * NBLK + bb * 128;   // 128 tiles per batch
    float s = 0.f;
#pragma unroll
    for (int k = 0; k < 8; ++k) s += p[j0 + 16 * k];
    for (int off = 8; off; off >>= 1) s += __shfl_down(s, off, 16);
    if (j0 == 0) red[group] = s;
    __syncthreads();

    if (tid < 4) {
        float accv = 0.f;
#pragma unroll
        for (int k = 0; k < 8; ++k)
            accv += red[tid * 16 + k] / red[tid * 16 + 8 + k];
        out[tid] = 8.0f - accv;
    }
}

extern "C" void kernel_launch(void* const* d_in, const int* in_sizes, int n_in,
                              void* d_out, int out_size, void* d_ws, size_t ws_size,
                              hipStream_t stream) {
    const float* batch = (const float*)d_in[0];
    const float* preds = (const float*)d_in[1];
    float* out      = (float*)d_out;
    float* partials = (float*)d_ws;   // 16*NBLK floats = 32 KB

    softncuts_main<<<dim3(NBLK), dim3(NT), 0, stream>>>(batch, preds, partials);
    softncuts_finalize<<<dim3(1), dim3(1024), 0, stream>>>(partials, out);
}